// Round 4
// baseline (615.485 us; speedup 1.0000x reference)
//
#include <hip/hip_runtime.h>
#include <math.h>

#define MAX_T 2048
#define SEG_P 4   // segments per 128-lane pool block

// ---- Kernel 1: fused score + per-batch segmentation ----
// Grid = B * nb blocks (nb = ceil(T/4)), 256 threads. Each wave computes one
// score row (64-lane float4 dot + shfl reduce + sigmoid). The last block to
// finish a batch (device-scope atomic counter) performs valley detection and
// the valley-index scan for that batch in LDS.
__global__ __launch_bounds__(256) void score_seg_kernel(
    const float* __restrict__ feat, const float* __restrict__ W,
    const float* __restrict__ bias, const int* __restrict__ hlens,
    float* __restrict__ score, int* __restrict__ vi_ws, int* __restrict__ hn_ws,
    float* __restrict__ hn_out, int* __restrict__ done,
    int T, int D, int M, int nb) {
  int b = blockIdx.x / nb;
  int rb = blockIdx.x - b * nb;
  int tid = threadIdx.x;
  int wid = tid >> 6, lane = tid & 63;
  int t = rb * 4 + wid;

  if (t < T) {
    const float4* f4 = (const float4*)(feat + ((size_t)b * T + t) * D);
    const float4* w4 = (const float4*)W;
    float acc = 0.f;
    int n4 = D >> 2;
    for (int idx = lane; idx < n4; idx += 64) {
      float4 a = f4[idx];
      float4 w = w4[idx];
      acc += a.x * w.x + a.y * w.y + a.z * w.z + a.w * w.w;
    }
#pragma unroll
    for (int off = 32; off > 0; off >>= 1) acc += __shfl_xor(acc, off, 64);
    if (lane == 0) {
      float x = acc + bias[0];
      score[(size_t)b * T + t] = 1.f / (1.f + expf(-x));
    }
  }

  // release own stores, then count this block done for batch b
  __threadfence();
  __shared__ int lastflag;
  __syncthreads();
  if (tid == 0) {
    int old = atomicAdd(&done[b], 1);
    lastflag = (old == nb - 1);
  }
  __syncthreads();
  if (!lastflag) return;
  __threadfence();  // acquire: other blocks' score stores now visible

  // ---- segmentation for batch b (all 256 threads) ----
  __shared__ float s[MAX_T];
  __shared__ unsigned char fl[MAX_T];
  __shared__ int vi[MAX_T];
  __shared__ int wsum[4];

  const float* sr = score + (size_t)b * T;
  int hl = hlens[b];
  for (int i = tid; i < T; i += 256) s[i] = sr[i];
  __syncthreads();

  for (int i = tid; i < T; i += 256) {
    bool f;
    if (i >= hl)               f = false;
    else if (i == 0 || i == hl - 1) f = true;
    else {
      float c = s[i];
      f = (c >= s[i - 1]) && (c >= s[i + 1]);
    }
    fl[i] = f ? (unsigned char)1 : (unsigned char)0;
  }
  __syncthreads();

  int C = (T + 255) / 256;
  int lo = tid * C;
  int hi = lo + C; if (hi > T) hi = T; if (lo > T) lo = T;
  int cnt = 0;
  for (int i = lo; i < hi; ++i) cnt += fl[i];

  int incl = cnt;
#pragma unroll
  for (int off = 1; off < 64; off <<= 1) {
    int v = __shfl_up(incl, off, 64);
    if (lane >= off) incl += v;
  }
  if (lane == 63) wsum[wid] = incl;
  __syncthreads();
  int wofs = 0;
#pragma unroll
  for (int w = 0; w < 4; ++w) wofs += (w < wid) ? wsum[w] : 0;
  int hn = wsum[0] + wsum[1] + wsum[2] + wsum[3];
  int excl = wofs + incl - cnt;
  for (int i = lo; i < hi; ++i) {
    if (fl[i]) vi[excl++] = i;
  }
  __syncthreads();

  for (int j = tid; j < M; j += 256) {
    vi_ws[(size_t)b * M + j] = (j < hn) ? vi[j] : 0;
  }
  if (tid == 0) {
    hn_ws[b] = hn;
    hn_out[b] = (float)hn;
  }
}

// ---- Kernel 2: grouped rolling-atom pool ----
// One 128-thread block per SEG_P consecutive segments of one batch.
// Atom j = [vi[j-1], vi[j]), vi[-1]:=0. Segment k = atom k U atom k+1
// (k < hn-1); segment hn-1 = atom hn-1. Rolling 2-atom register window.
__global__ __launch_bounds__(128) void pool_kernel(
    const float* __restrict__ feat, const float* __restrict__ score,
    const int* __restrict__ vi_ws, const int* __restrict__ hn_ws,
    float* __restrict__ out, int T, int D, int M, int ngrp) {
  int gid = blockIdx.x;
  int lane = threadIdx.x;                 // 128 lanes, float4 covers D=512
  int b = gid / ngrp;
  int g = gid - b * ngrp;
  int k0 = g * SEG_P;
  if (k0 >= M) return;

  int hn = hn_ws[b];
  const int* vi = vi_ws + (size_t)b * M;
  const float* sr = score + (size_t)b * T;
  const float4* fr = (const float4*)(feat + (size_t)b * T * (size_t)D);
  int n4 = D >> 2;                        // 128

  int kend = k0 + SEG_P; if (kend > M) kend = M;

  float4 ap = make_float4(0.f, 0.f, 0.f, 0.f);
  float ssp = 0.f;
  if (k0 < hn) {
    int as = (k0 == 0) ? 0 : vi[k0 - 1];
    int ae = vi[k0];
    for (int t = as; t < ae; ++t) {
      float sc = sr[t];
      float4 f = fr[(size_t)t * n4 + lane];
      ap.x += sc * f.x; ap.y += sc * f.y; ap.z += sc * f.z; ap.w += sc * f.w;
      ssp += sc;
    }
  }

  for (int k = k0; k < kend; ++k) {
    float4* o4 = (float4*)(out + ((size_t)b * M + k) * D);
    if (k >= hn) {
      o4[lane] = make_float4(0.f, 0.f, 0.f, 0.f);
      continue;
    }
    if (k == hn - 1) {
      float inv = 1.f / (ssp + 1e-10f);
      o4[lane] = make_float4(ap.x * inv, ap.y * inv, ap.z * inv, ap.w * inv);
      ssp = 0.f; ap = make_float4(0.f, 0.f, 0.f, 0.f);
      continue;
    }
    float4 ac = make_float4(0.f, 0.f, 0.f, 0.f);
    float ssc = 0.f;
    int as = vi[k];
    int ae = vi[k + 1];
    for (int t = as; t < ae; ++t) {
      float sc = sr[t];
      float4 f = fr[(size_t)t * n4 + lane];
      ac.x += sc * f.x; ac.y += sc * f.y; ac.z += sc * f.z; ac.w += sc * f.w;
      ssc += sc;
    }
    float inv = 1.f / (ssp + ssc + 1e-10f);
    o4[lane] = make_float4((ap.x + ac.x) * inv, (ap.y + ac.y) * inv,
                           (ap.z + ac.z) * inv, (ap.w + ac.w) * inv);
    ap = ac; ssp = ssc;
  }
}

extern "C" void kernel_launch(void* const* d_in, const int* in_sizes, int n_in,
                              void* d_out, int out_size, void* d_ws, size_t ws_size,
                              hipStream_t stream) {
  const float* feat = (const float*)d_in[0];
  const float* W    = (const float*)d_in[1];
  const float* bias = (const float*)d_in[2];
  const int* hlens  = (const int*)d_in[3];

  int D = in_sizes[1];                 // 512
  int B = in_sizes[3];                 // 16
  int T = in_sizes[0] / (B * D);       // 2000
  int M = (out_size - B - B * T) / (B * D);  // data-dependent max segments

  float* out      = (float*)d_out;
  float* hn_out   = out + (size_t)B * M * D;      // [B] (as float)
  float* score    = hn_out + B;                   // [B, T]

  // ws: done[B] | hn_ws[B] | vi[B*M]
  int* done  = (int*)d_ws;
  int* hn_ws = done + B;
  int* vi_ws = hn_ws + B;

  hipMemsetAsync(done, 0, B * sizeof(int), stream);

  int nb = (T + 3) / 4;
  score_seg_kernel<<<B * nb, 256, 0, stream>>>(feat, W, bias, hlens, score,
                                               vi_ws, hn_ws, hn_out, done,
                                               T, D, M, nb);

  int ngrp = (M + SEG_P - 1) / SEG_P;
  pool_kernel<<<B * ngrp, 128, 0, stream>>>(feat, score, vi_ws, hn_ws,
                                            out, T, D, M, ngrp);
}

// Round 5
// 35.290 us; speedup vs baseline: 17.4406x; 17.4406x over previous
//
#include <hip/hip_runtime.h>
#include <math.h>

#define MAX_T 2048
#define SEG_P 4   // segments per 128-lane pool block

// ---------------- Kernel 1: score = sigmoid(feat . W + b) ----------------
// One wave (64 lanes) per (b,t) row. float4 coalesced loads.
__global__ void score_kernel(const float* __restrict__ feat,
                             const float* __restrict__ W,
                             const float* __restrict__ bias,
                             float* __restrict__ score,
                             int nrows, int D) {
  int row = blockIdx.x * 4 + (threadIdx.x >> 6);
  int lane = threadIdx.x & 63;
  if (row >= nrows) return;
  const float4* f4 = (const float4*)(feat + (size_t)row * D);
  const float4* w4 = (const float4*)W;
  float acc = 0.f;
  int n4 = D >> 2;
  for (int idx = lane; idx < n4; idx += 64) {
    float4 a = f4[idx];
    float4 w = w4[idx];
    acc += a.x * w.x + a.y * w.y + a.z * w.z + a.w * w.w;
  }
#pragma unroll
  for (int off = 32; off > 0; off >>= 1) acc += __shfl_xor(acc, off, 64);
  if (lane == 0) {
    float x = acc + bias[0];
    score[row] = 1.f / (1.f + expf(-x));
  }
}

// ---------------- Kernel 2: valley detect -> vi table ----------------
// One block (256 threads) per batch element. vi[j] = frame index of valley j.
// Atom j := [vi[j-1], vi[j]) with vi[-1]:=0 (atom 0 empty since vi[0]==0).
// Segment k = atom k U atom k+1 (k<hn-1); segment hn-1 = atom hn-1
// (because vi[hn-1] == hl-1 is the forced last valley).
__global__ void seg_kernel(const float* __restrict__ score,
                           const int* __restrict__ hlens,
                           int* __restrict__ vi_ws,
                           int* __restrict__ hn_ws,
                           float* __restrict__ hn_out,
                           int T, int M) {
  int b = blockIdx.x;
  int tid = threadIdx.x;
  __shared__ float s[MAX_T];
  __shared__ unsigned char fl[MAX_T];
  __shared__ int vi[MAX_T];
  __shared__ int wsum[4];

  const float* sr = score + (size_t)b * T;
  int hl = hlens[b];

  for (int t = tid; t < T; t += 256) s[t] = sr[t];
  __syncthreads();

  for (int t = tid; t < T; t += 256) {
    bool f;
    if (t >= hl) {
      f = false;
    } else if (t == 0 || t == hl - 1) {
      f = true;
    } else {
      float c = s[t];
      f = (c >= s[t - 1]) && (c >= s[t + 1]);
    }
    fl[t] = f ? (unsigned char)1 : (unsigned char)0;
  }
  __syncthreads();

  // blocked scan: per-thread chunk count -> wave shfl scan -> 4-wave combine
  int C = (T + 255) / 256;
  int lo = tid * C;
  int hi = lo + C; if (hi > T) hi = T; if (lo > T) lo = T;
  int cnt = 0;
  for (int t = lo; t < hi; ++t) cnt += fl[t];

  int lane = tid & 63, wid = tid >> 6;
  int incl = cnt;
#pragma unroll
  for (int off = 1; off < 64; off <<= 1) {
    int v = __shfl_up(incl, off, 64);
    if (lane >= off) incl += v;
  }
  if (lane == 63) wsum[wid] = incl;
  __syncthreads();
  int wofs = 0;
#pragma unroll
  for (int w = 0; w < 4; ++w) wofs += (w < wid) ? wsum[w] : 0;
  int hn = wsum[0] + wsum[1] + wsum[2] + wsum[3];
  int excl = wofs + incl - cnt;
  for (int t = lo; t < hi; ++t) {
    if (fl[t]) vi[excl++] = t;
  }
  __syncthreads();

  for (int j = tid; j < M; j += 256) {
    vi_ws[(size_t)b * M + j] = (j < hn) ? vi[j] : 0;
  }
  if (tid == 0) {
    hn_ws[b] = hn;
    hn_out[b] = (float)hn;
  }
}

// ---------------- Kernel 3: grouped rolling-atom pool ----------------
// One 128-thread block per SEG_P consecutive segments of one batch.
// Rolling 2-atom register window; feat read (SEG_P+1)/SEG_P times, mostly L3.
__global__ __launch_bounds__(128) void pool_kernel(
    const float* __restrict__ feat, const float* __restrict__ score,
    const int* __restrict__ vi_ws, const int* __restrict__ hn_ws,
    float* __restrict__ out, int T, int D, int M, int ngrp) {
  int gid = blockIdx.x;
  int lane = threadIdx.x;                 // 128 lanes, float4 covers D=512
  int b = gid / ngrp;
  int g = gid - b * ngrp;
  int k0 = g * SEG_P;
  if (k0 >= M) return;

  int hn = hn_ws[b];
  const int* vi = vi_ws + (size_t)b * M;
  const float* sr = score + (size_t)b * T;
  const float4* fr = (const float4*)(feat + (size_t)b * T * (size_t)D);
  int n4 = D >> 2;                        // 128

  int kend = k0 + SEG_P; if (kend > M) kend = M;

  float4 ap = make_float4(0.f, 0.f, 0.f, 0.f);
  float ssp = 0.f;
  if (k0 < hn) {
    int as = (k0 == 0) ? 0 : vi[k0 - 1];
    int ae = vi[k0];
    for (int t = as; t < ae; ++t) {
      float sc = sr[t];
      float4 f = fr[(size_t)t * n4 + lane];
      ap.x += sc * f.x; ap.y += sc * f.y; ap.z += sc * f.z; ap.w += sc * f.w;
      ssp += sc;
    }
  }

  for (int k = k0; k < kend; ++k) {
    float4* o4 = (float4*)(out + ((size_t)b * M + k) * D);
    if (k >= hn) {
      o4[lane] = make_float4(0.f, 0.f, 0.f, 0.f);
      continue;
    }
    if (k == hn - 1) {
      float inv = 1.f / (ssp + 1e-10f);
      o4[lane] = make_float4(ap.x * inv, ap.y * inv, ap.z * inv, ap.w * inv);
      ssp = 0.f; ap = make_float4(0.f, 0.f, 0.f, 0.f);
      continue;
    }
    float4 ac = make_float4(0.f, 0.f, 0.f, 0.f);
    float ssc = 0.f;
    int as = vi[k];
    int ae = vi[k + 1];
    for (int t = as; t < ae; ++t) {
      float sc = sr[t];
      float4 f = fr[(size_t)t * n4 + lane];
      ac.x += sc * f.x; ac.y += sc * f.y; ac.z += sc * f.z; ac.w += sc * f.w;
      ssc += sc;
    }
    float inv = 1.f / (ssp + ssc + 1e-10f);
    o4[lane] = make_float4((ap.x + ac.x) * inv, (ap.y + ac.y) * inv,
                           (ap.z + ac.z) * inv, (ap.w + ac.w) * inv);
    ap = ac; ssp = ssc;
  }
}

extern "C" void kernel_launch(void* const* d_in, const int* in_sizes, int n_in,
                              void* d_out, int out_size, void* d_ws, size_t ws_size,
                              hipStream_t stream) {
  const float* feat = (const float*)d_in[0];
  const float* W    = (const float*)d_in[1];
  const float* bias = (const float*)d_in[2];
  const int* hlens  = (const int*)d_in[3];

  int D = in_sizes[1];                 // 512
  int B = in_sizes[3];                 // 16
  int T = in_sizes[0] / (B * D);       // 2000
  int M = (out_size - B - B * T) / (B * D);  // data-dependent max segments

  float* out      = (float*)d_out;
  float* hn_out   = out + (size_t)B * M * D;      // [B] (as float)
  float* score    = hn_out + B;                   // [B, T]

  // ws layout: vi[B*M] int | hn_ws[B] int
  int* vi_ws = (int*)d_ws;
  int* hn_ws = vi_ws + (size_t)B * M;

  int nrows = B * T;
  score_kernel<<<(nrows + 3) / 4, 256, 0, stream>>>(feat, W, bias, score, nrows, D);
  seg_kernel<<<B, 256, 0, stream>>>(score, hlens, vi_ws, hn_ws, hn_out, T, M);

  int ngrp = (M + SEG_P - 1) / SEG_P;
  pool_kernel<<<B * ngrp, 128, 0, stream>>>(feat, score, vi_ws, hn_ws,
                                            out, T, D, M, ngrp);
}